// Round 2
// baseline (886.421 us; speedup 1.0000x reference)
//
#include <hip/hip_runtime.h>

#define SEQ 128
#define HID 2048
#define DIM 768

typedef float f32x4 __attribute__((ext_vector_type(4)));

// ---------------- k1: act[s][h] = relu(x[s,:] . We[h,:] + be[h]) ----------------
// wave computes a 4s x 4h tile; lanes cover K=768 as 3 chunks of 256 (float4/lane)
__global__ __launch_bounds__(256) void enc_kernel(const float* __restrict__ x,
                                                  const float* __restrict__ We,
                                                  const float* __restrict__ be,
                                                  float* __restrict__ act) {
    const int lane = threadIdx.x & 63;
    const int gw   = blockIdx.x * 4 + (threadIdx.x >> 6);   // global wave id
    const int st   = gw >> 9;          // 32 s-tiles
    const int ht   = gw & 511;         // 512 h-tiles
    const int s0 = st * 4, h0 = ht * 4;

    float acc[4][4] = {};
#pragma unroll
    for (int c = 0; c < 3; ++c) {
        const int kk = c * 256 + lane * 4;
        f32x4 xa[4], wb[4];
#pragma unroll
        for (int j = 0; j < 4; ++j)
            xa[j] = *(const f32x4*)(x + (s0 + j) * DIM + kk);
#pragma unroll
        for (int i = 0; i < 4; ++i)
            wb[i] = *(const f32x4*)(We + (h0 + i) * DIM + kk);
#pragma unroll
        for (int j = 0; j < 4; ++j)
#pragma unroll
            for (int i = 0; i < 4; ++i)
                acc[j][i] += xa[j].x * wb[i].x + xa[j].y * wb[i].y +
                             xa[j].z * wb[i].z + xa[j].w * wb[i].w;
    }
#pragma unroll
    for (int j = 0; j < 4; ++j)
#pragma unroll
        for (int i = 0; i < 4; ++i) {
            float v = acc[j][i];
#pragma unroll
            for (int off = 32; off >= 1; off >>= 1) v += __shfl_xor(v, off);
            if (lane == 0) {
                const int h = h0 + i;
                act[(s0 + j) * HID + h] = fmaxf(v + be[h], 0.0f);
            }
        }
}

// ---------------- k2: feat[s][h][d] = act[s][h] * Wd[d][h] ----------------
// one block per h; 192 threads each own 4 consecutive d (float4);
// loop over s with coalesced nontemporal float4 stores (1KB per wave-instr)
__global__ __launch_bounds__(192) void feat_kernel(const float* __restrict__ act,
                                                   const float* __restrict__ Wd,
                                                   float* __restrict__ feat) {
    const int h = blockIdx.x;
    const int t = threadIdx.x;            // 0..191
    __shared__ float acol[SEQ];

    f32x4 w;
    w.x = Wd[(size_t)(4 * t + 0) * HID + h];
    w.y = Wd[(size_t)(4 * t + 1) * HID + h];
    w.z = Wd[(size_t)(4 * t + 2) * HID + h];
    w.w = Wd[(size_t)(4 * t + 3) * HID + h];
    if (t < SEQ) acol[t] = act[t * HID + h];
    __syncthreads();

    float* p = feat + (size_t)h * DIM + 4 * t;
#pragma unroll 4
    for (int s = 0; s < SEQ; ++s) {
        const float a = acol[s];
        f32x4 o;
        o.x = a * w.x; o.y = a * w.y; o.z = a * w.z; o.w = a * w.w;
        __builtin_nontemporal_store(o, (f32x4*)p);
        p += (size_t)HID * DIM;
    }
}

// ---------------- k3: recon[s][d] = act[s,:] . Wd[d,:] + bd[d] ----------------
// wave computes 4s x 4d tile; K=2048 as 8 chunks of 256 (float4/lane)
__global__ __launch_bounds__(256) void dec_kernel(const float* __restrict__ act,
                                                  const float* __restrict__ Wd,
                                                  const float* __restrict__ bd,
                                                  float* __restrict__ recon) {
    const int lane = threadIdx.x & 63;
    const int gw   = blockIdx.x * 4 + (threadIdx.x >> 6);
    const int st   = gw / 192;            // 32 s-tiles
    const int dt   = gw % 192;            // 192 d-tiles
    const int s0 = st * 4, d0 = dt * 4;

    float acc[4][4] = {};
#pragma unroll
    for (int c = 0; c < 8; ++c) {
        const int kk = c * 256 + lane * 4;
        f32x4 a4[4], w4[4];
#pragma unroll
        for (int j = 0; j < 4; ++j)
            a4[j] = *(const f32x4*)(act + (s0 + j) * HID + kk);
#pragma unroll
        for (int i = 0; i < 4; ++i)
            w4[i] = *(const f32x4*)(Wd + (d0 + i) * HID + kk);
#pragma unroll
        for (int j = 0; j < 4; ++j)
#pragma unroll
            for (int i = 0; i < 4; ++i)
                acc[j][i] += a4[j].x * w4[i].x + a4[j].y * w4[i].y +
                             a4[j].z * w4[i].z + a4[j].w * w4[i].w;
    }
#pragma unroll
    for (int j = 0; j < 4; ++j)
#pragma unroll
        for (int i = 0; i < 4; ++i) {
            float v = acc[j][i];
#pragma unroll
            for (int off = 32; off >= 1; off >>= 1) v += __shfl_xor(v, off);
            if (lane == 0)
                recon[(s0 + j) * DIM + d0 + i] = v + bd[d0 + i];
        }
}

extern "C" void kernel_launch(void* const* d_in, const int* in_sizes, int n_in,
                              void* d_out, int out_size, void* d_ws, size_t ws_size,
                              hipStream_t stream) {
    const float* x  = (const float*)d_in[0];   // [1,128,768]
    const float* We = (const float*)d_in[1];   // [2048,768]
    const float* be = (const float*)d_in[2];   // [2048]
    const float* Wd = (const float*)d_in[3];   // [768,2048]
    const float* bd = (const float*)d_in[4];   // [768]

    float* recon = (float*)d_out;              // [128,768]
    float* feat  = recon + SEQ * DIM;          // [128,2048,768]
    float* act   = (float*)d_ws;               // [128,2048] scratch (1 MB)

    // k1: encoder GEMM + ReLU  (32*512 wave-tiles, 4 waves/block)
    hipLaunchKernelGGL(enc_kernel, dim3(4096), dim3(256), 0, stream, x, We, be, act);
    // k2: feature-vector writer (805 MB stream) — one block per h
    hipLaunchKernelGGL(feat_kernel, dim3(HID), dim3(192), 0, stream, act, Wd, feat);
    // k3: decoder GEMM + bias  (32*192 wave-tiles, 4 waves/block)
    hipLaunchKernelGGL(dec_kernel, dim3(1536), dim3(256), 0, stream, act, Wd, bd, recon);
}